// Round 3
// baseline (398.737 us; speedup 1.0000x reference)
//
#include <hip/hip_runtime.h>
#include <hip/hip_cooperative_groups.h>

namespace cg = cooperative_groups;

// Problem constants (static shapes from reference)
#define B 64
#define C 2048
#define H 24
#define W 8
#define HW (H * W)            // 192 spatial positions per (b,c)
#define HW4 (HW / 4)          // 48 float4 per channel row
#define CHUNKS 16             // channel chunks per batch
#define CPC (C / CHUNKS)      // 128 channels per chunk
#define RH 8                  // round(0.33 * 24) = 8 rows zeroed
#define CHW4 ((C * HW) / 4)   // float4s per batch = 98304

#define GRID (B * CHUNKS)     // 1024 blocks, one (b,chunk) task each; 4 blocks/CU
#define TPB 192               // 3 waves
#define BPB (GRID / B)        // 16 phase-3 blocks per batch
#define SLICE (CHW4 / BPB)    // 6144 float4 per block; 6144 % 48 == 0
#define ITERS (SLICE / TPB)   // 32 float4 per thread

typedef float f32x4 __attribute__((ext_vector_type(4)));

// ---------------------------------------------------------------------------
// Fused cooperative kernel: sumsq partials -> grid sync -> mask -> grid sync
// -> apply. Phases 1/2 are bit-identical reproductions of the verified k_ss /
// k_mask (same summation order, same tie-break), so absmax stays 0.
// ---------------------------------------------------------------------------
__global__ __launch_bounds__(TPB) void k_fused(const f32x4* __restrict__ x4,
                                               f32x4* __restrict__ partial4,
                                               float* __restrict__ mask,
                                               f32x4* __restrict__ out4) {
    const int blk = blockIdx.x;
    const int t = threadIdx.x;

    // ---- Phase 1: sum of squares for this block's (b, chunk) ----
    {
        const int b = blk / CHUNKS;
        const int chunk = blk % CHUNKS;
        const int q = t % HW4;   // float4 spatial position
        const int g = t / HW4;   // channel subgroup (0..3)
        const f32x4* p = x4 + (size_t)(b * C + chunk * CPC + g) * HW4 + q;
        f32x4 acc = {0.f, 0.f, 0.f, 0.f};
        #pragma unroll
        for (int j = 0; j < CPC / 4; ++j) {          // 32 iterations
            const f32x4 v = p[(size_t)j * 4 * HW4];  // 16 B/lane, coalesced
            acc += v * v;
        }
        __shared__ f32x4 sm[4][HW4];  // 3 KB
        sm[g][q] = acc;
        __syncthreads();
        if (t < HW4)
            partial4[(size_t)blk * HW4 + t] =
                (sm[0][t] + sm[1][t]) + (sm[2][t] + sm[3][t]);
    }

    cg::this_grid().sync();

    // ---- Phase 2: mask for batch blk (blocks 0..63, wave 0 only) ----
    // LDS-free: row maxima live on even lanes < 48; gather via shuffles.
    if (blk < B && t < 64) {
        f32x4 s = {0.f, 0.f, 0.f, 0.f};
        if (t < HW4) {
            #pragma unroll
            for (int ch = 0; ch < CHUNKS; ++ch)  // fixed order: deterministic
                s += partial4[(size_t)(blk * CHUNKS + ch) * HW4 + t];
        }
        float m = fmaxf(fmaxf(s.x, s.y), fmaxf(s.z, s.w));
        m = fmaxf(m, __shfl_xor(m, 1));  // row h max now at lane 2h
        const float my = __shfl(m, 2 * (t < H ? t : 0));
        int cnt = 0;
        #pragma unroll
        for (int h = 0; h < H; ++h) {
            const float o = __shfl(m, 2 * h);
            if (o > my || (o == my && h > t)) ++cnt;  // stable-argsort tie-break
        }
        if (t < H) mask[blk * H + t] = (cnt < RH) ? 0.0f : 1.0f;
    }

    cg::this_grid().sync();

    // ---- Phase 3: out = x * mask. Block-stride ≡ 0 mod 48 -> each thread's
    // h is CONSTANT: one mask load, then pure load·mul·NT-store. x re-read
    // hits L3; out never re-read -> nontemporal store. ----
    {
        const int b = blk / BPB;
        const int sub = blk % BPB;
        const size_t base = (size_t)b * CHW4 + (size_t)sub * SLICE + t;
        const int h = (t % (2 * H)) >> 1;  // (idx4 % 48) >> 1, constant per thread
        const float m = mask[b * H + h];
        #pragma unroll 4
        for (int k = 0; k < ITERS; ++k) {
            const size_t e = base + (size_t)k * TPB;
            __builtin_nontemporal_store(x4[e] * m, (f32x4*)(out4 + e));
        }
    }
}

// ---------------------------------------------------------------------------
// Fallback path (proven Round-2 kernels) in case cooperative launch is
// rejected by the runtime/capture. Bit-identical results.
// ---------------------------------------------------------------------------
__global__ __launch_bounds__(192) void k_ss(const f32x4* __restrict__ x4,
                                            f32x4* __restrict__ partial4) {
    const int blk = blockIdx.x;
    const int b = blk / CHUNKS;
    const int chunk = blk % CHUNKS;
    const int t = threadIdx.x;
    const int q = t % HW4;
    const int g = t / HW4;
    const f32x4* p = x4 + (size_t)(b * C + chunk * CPC + g) * HW4 + q;
    f32x4 acc = {0.f, 0.f, 0.f, 0.f};
    #pragma unroll
    for (int j = 0; j < CPC / 4; ++j) {
        const f32x4 v = p[(size_t)j * 4 * HW4];
        acc += v * v;
    }
    __shared__ f32x4 sm[4][HW4];
    sm[g][q] = acc;
    __syncthreads();
    if (t < HW4)
        partial4[(size_t)blk * HW4 + t] = (sm[0][t] + sm[1][t]) + (sm[2][t] + sm[3][t]);
}

__global__ __launch_bounds__(64) void k_mask(const f32x4* __restrict__ partial4,
                                             float* __restrict__ mask) {
    __shared__ float rs[H];
    const int b = blockIdx.x;
    const int t = threadIdx.x;
    if (t < HW4) {
        f32x4 s = {0.f, 0.f, 0.f, 0.f};
        #pragma unroll
        for (int ch = 0; ch < CHUNKS; ++ch)
            s += partial4[(size_t)(b * CHUNKS + ch) * HW4 + t];
        float m = fmaxf(fmaxf(s.x, s.y), fmaxf(s.z, s.w));
        m = fmaxf(m, __shfl_xor(m, 1));
        if ((t & 1) == 0) rs[t >> 1] = m;
    }
    __syncthreads();
    if (t < H) {
        const float my = rs[t];
        int cnt = 0;
        #pragma unroll
        for (int h = 0; h < H; ++h) {
            const float o = rs[h];
            if (o > my || (o == my && h > t)) ++cnt;
        }
        mask[b * H + t] = (cnt < RH) ? 0.0f : 1.0f;
    }
}

__global__ __launch_bounds__(256) void k_apply(const f32x4* __restrict__ x4,
                                               const float* __restrict__ mask,
                                               f32x4* __restrict__ out4) {
    const int b = blockIdx.y;
    const int idx4 = blockIdx.x * 256 + threadIdx.x;
    const int h = (idx4 >> 1) % H;
    const float m = mask[b * H + h];
    const size_t e = (size_t)b * CHW4 + idx4;
    __builtin_nontemporal_store(x4[e] * m, (f32x4*)(out4 + e));
}

// ---------------------------------------------------------------------------
extern "C" void kernel_launch(void* const* d_in, const int* in_sizes, int n_in,
                              void* d_out, int out_size, void* d_ws, size_t ws_size,
                              hipStream_t stream) {
    const f32x4* x4 = (const f32x4*)d_in[0];
    f32x4* out4 = (f32x4*)d_out;
    f32x4* partial4 = (f32x4*)d_ws;                         // B*CHUNKS*HW floats (768 KB)
    float* mask = (float*)d_ws + (size_t)B * CHUNKS * HW;   // B*H floats

    void* args[] = {(void*)&x4, (void*)&partial4, (void*)&mask, (void*)&out4};
    const hipError_t err = hipLaunchCooperativeKernel(
        (const void*)k_fused, dim3(GRID), dim3(TPB), args, 0, stream);

    if (err != hipSuccess) {
        // Cooperative launch unavailable: proven 3-kernel path.
        k_ss<<<B * CHUNKS, 192, 0, stream>>>(x4, partial4);
        k_mask<<<B, 64, 0, stream>>>(partial4, mask);
        k_apply<<<dim3(CHW4 / 256, B), 256, 0, stream>>>(x4, mask, out4);
    }
}

// Round 5
// 189.322 us; speedup vs baseline: 2.1061x; 2.1061x over previous
//
#include <hip/hip_runtime.h>

// Problem constants (static shapes from reference)
#define B 64
#define C 2048
#define H 24
#define W 8
#define HW (H * W)            // 192 spatial positions per (b,c)
#define HW4 (HW / 4)          // 48 float4 per channel row
#define CHUNKS 16             // channel chunks per batch
#define CPC (C / CHUNKS)      // 128 channels per chunk
#define RH 8                  // round(0.33 * 24) = 8 rows zeroed
#define CHW4 ((C * HW) / 4)   // float4s per batch = 98304
#define TPB 192               // 3 waves
#define BPB 16                // apply-blocks per batch
#define SLICE (CHW4 / BPB)    // 6144 float4 per block (6144 % 48 == 0)
#define ITERS (SLICE / TPB)   // 32 float4 per thread
#define PF 8                  // prefetched float4 per thread (32 VGPR)

typedef float f32x4 __attribute__((ext_vector_type(4)));

// ---------------------------------------------------------------------------
// Kernel A: partial sum of squares over a channel chunk (verbatim from the
// verified Round-2 build). grid = B*CHUNKS, block = 192 (3 waves).
// 16 B/lane coalesced dwordx4 loads; LDS reduce across 4 channel subgroups.
// ---------------------------------------------------------------------------
__global__ __launch_bounds__(TPB) void k_ss(const f32x4* __restrict__ x4,
                                            f32x4* __restrict__ partial4) {
    const int blk = blockIdx.x;
    const int b = blk / CHUNKS;
    const int chunk = blk % CHUNKS;
    const int t = threadIdx.x;
    const int q = t % HW4;   // float4 spatial position
    const int g = t / HW4;   // channel subgroup (0..3)

    const f32x4* p = x4 + (size_t)(b * C + chunk * CPC + g) * HW4 + q;
    f32x4 acc = {0.f, 0.f, 0.f, 0.f};
    #pragma unroll
    for (int j = 0; j < CPC / 4; ++j) {          // 32 iters
        const f32x4 v = p[(size_t)j * 4 * HW4];
        acc += v * v;
    }
    __shared__ f32x4 sm[4][HW4];  // 3 KB
    sm[g][q] = acc;
    __syncthreads();
    if (t < HW4)
        partial4[(size_t)blk * HW4 + t] =
            (sm[0][t] + sm[1][t]) + (sm[2][t] + sm[3][t]);
}

// ---------------------------------------------------------------------------
// Kernel B: fused mask + apply. grid = B*BPB blocks, block = 192.
// Each block REDUNDANTLY ranks its batch's rows from the 12 KB of partials
// (L2-resident; shuffle math verbatim from the Round-3 kernel that passed
// with absmax 0), then applies the mask to its 98 KB slice of x.
// The first PF float4 of the slice are prefetched into registers BEFORE the
// barrier, so their HBM latency hides under wave 0's mask computation.
// No cross-block sync anywhere -> hang-proof.
// ---------------------------------------------------------------------------
__global__ __launch_bounds__(TPB) void k_mask_apply(const f32x4* __restrict__ x4,
                                                    const f32x4* __restrict__ partial4,
                                                    f32x4* __restrict__ out4) {
    const int blk = blockIdx.x;
    const int b = blk / BPB;
    const int sub = blk % BPB;
    const int t = threadIdx.x;
    __shared__ float smask[H];

    // ---- Prefetch (independent of mask; overlaps the rank phase) ----
    const size_t base = (size_t)b * CHW4 + (size_t)sub * SLICE + t;
    f32x4 pf[PF];
    #pragma unroll
    for (int k = 0; k < PF; ++k) pf[k] = x4[base + (size_t)k * TPB];

    // ---- Rank rows (wave 0 only; verbatim verified math) ----
    if (t < 64) {
        f32x4 s = {0.f, 0.f, 0.f, 0.f};
        if (t < HW4) {
            #pragma unroll
            for (int ch = 0; ch < CHUNKS; ++ch)  // fixed order: deterministic
                s += partial4[(size_t)(b * CHUNKS + ch) * HW4 + t];
        }
        float m = fmaxf(fmaxf(s.x, s.y), fmaxf(s.z, s.w));
        m = fmaxf(m, __shfl_xor(m, 1));  // row h max now at lane 2h
        const float my = __shfl(m, 2 * (t < H ? t : 0));
        int cnt = 0;
        #pragma unroll
        for (int h = 0; h < H; ++h) {
            const float o = __shfl(m, 2 * h);
            if (o > my || (o == my && h > t)) ++cnt;  // stable-argsort tie-break
        }
        if (t < H) smask[t] = (cnt < RH) ? 0.0f : 1.0f;
    }
    __syncthreads();

    // ---- Apply. Block stride ≡ 0 mod 48 -> h is CONSTANT per thread. ----
    const float m = smask[(t % (2 * H)) >> 1];
    #pragma unroll
    for (int k = 0; k < PF; ++k)
        __builtin_nontemporal_store(pf[k] * m, (f32x4*)(out4 + base + (size_t)k * TPB));
    #pragma unroll
    for (int k = PF; k < ITERS; ++k) {
        const size_t e = base + (size_t)k * TPB;
        __builtin_nontemporal_store(x4[e] * m, (f32x4*)(out4 + e));
    }
}

// ---------------------------------------------------------------------------
extern "C" void kernel_launch(void* const* d_in, const int* in_sizes, int n_in,
                              void* d_out, int out_size, void* d_ws, size_t ws_size,
                              hipStream_t stream) {
    const f32x4* x4 = (const f32x4*)d_in[0];
    f32x4* out4 = (f32x4*)d_out;
    f32x4* partial4 = (f32x4*)d_ws;  // B*CHUNKS*HW floats (768 KB)

    k_ss<<<B * CHUNKS, TPB, 0, stream>>>(x4, partial4);
    k_mask_apply<<<B * BPB, TPB, 0, stream>>>(x4, partial4, out4);
}